// Round 2
// baseline (143.611 us; speedup 1.0000x reference)
//
#include <hip/hip_runtime.h>

#define B_ 4
#define S_ 1024
#define D_ 1024
#define H_ 16
#define DH_ 64

typedef unsigned short u16;
typedef __attribute__((ext_vector_type(8))) short bf16x8;
typedef __attribute__((ext_vector_type(4))) float f32x4;

__device__ __forceinline__ float bf2f(u16 h){
  union { unsigned u; float f; } x; x.u = ((unsigned)h) << 16; return x.f;
}
__device__ __forceinline__ u16 f2bf(float f){
  union { float f; unsigned u; } x; x.f = f;
  unsigned u = x.u;
  return (u16)((u + 0x7fffu + ((u >> 16) & 1u)) >> 16);
}

__device__ __forceinline__ void gload16(const u16* g, u16* l){
  __builtin_amdgcn_global_load_lds(
      (const __attribute__((address_space(1))) unsigned int*)g,
      (__attribute__((address_space(3))) unsigned int*)l, 16, 0, 0);
}

// ---------------- cast fp32 -> bf16 (n % 4 == 0) ----------------
__global__ __launch_bounds__(256) void cast_bf16(const float* __restrict__ in,
                                                 u16* __restrict__ out, int n){
  int i = (blockIdx.x * 256 + threadIdx.x) * 4;
  if (i >= n) return;
  float4 v = *(const float4*)(in + i);
  union { u16 s[4]; uint2 u; } o;
  o.s[0] = f2bf(v.x); o.s[1] = f2bf(v.y); o.s[2] = f2bf(v.z); o.s[3] = f2bf(v.w);
  *(uint2*)(out + i) = o.u;
}

// ---------------- GEMM: C[m][n] = sum_k A[m][k]*Bm[n][k] + bias[n] ----------------
// A: M x K bf16 row-major, Bm: N x K bf16 row-major (the "B^T" pattern).
// 128x128 tile, BK=32, 4 waves (2x2 of 64x64), double-buffered global_load_lds.
template<int OUT_BF16>
__global__ __launch_bounds__(256) void gemm_bt(const u16* __restrict__ A,
    const u16* __restrict__ Bm, const float* __restrict__ bias,
    void* __restrict__ Cout, int M, int N, int K){
  __shared__ u16 As[2][128*32];
  __shared__ u16 Bs[2][128*32];
  const int tid = threadIdx.x;
  const int lane = tid & 63;
  const int w = tid >> 6;
  const int wr = w >> 1, wc = w & 1;
  const int lo = lane & 15, g = lane >> 4;
  const int m0 = blockIdx.x * 128, n0 = blockIdx.y * 128;

  f32x4 acc[4][4];
  #pragma unroll
  for (int i = 0; i < 4; ++i)
    #pragma unroll
    for (int j = 0; j < 4; ++j) acc[i][j] = (f32x4){0.f, 0.f, 0.f, 0.f};

  const int nt = K >> 5;

  auto stage = [&](int buf, int kt){
    const u16* ga = A + (size_t)m0 * K + kt * 32;
    const u16* gb = Bm + (size_t)n0 * K + kt * 32;
    #pragma unroll
    for (int it = 0; it < 2; ++it){
      int chunk = tid + it * 256;       // 0..511
      int row = chunk >> 2;             // 128 rows
      int c0 = (chunk & 3) * 8;         // 4 chunks of 8 bf16 per row
      gload16(ga + (size_t)row * K + c0, &As[buf][chunk * 8]);
      gload16(gb + (size_t)row * K + c0, &Bs[buf][chunk * 8]);
    }
  };

  stage(0, 0);
  __syncthreads();
  int buf = 0;
  for (int kt = 0; kt < nt; ++kt){
    if (kt + 1 < nt) stage(buf ^ 1, kt + 1);
    bf16x8 af[4], bfr[4];
    #pragma unroll
    for (int mi = 0; mi < 4; ++mi)
      af[mi] = *(const bf16x8*)(&As[buf][(wr*64 + mi*16 + lo)*32 + g*8]);
    #pragma unroll
    for (int ni = 0; ni < 4; ++ni)
      bfr[ni] = *(const bf16x8*)(&Bs[buf][(wc*64 + ni*16 + lo)*32 + g*8]);
    #pragma unroll
    for (int mi = 0; mi < 4; ++mi)
      #pragma unroll
      for (int ni = 0; ni < 4; ++ni)
        acc[mi][ni] = __builtin_amdgcn_mfma_f32_16x16x32_bf16(af[mi], bfr[ni], acc[mi][ni], 0, 0, 0);
    __syncthreads();
    buf ^= 1;
  }

  // epilogue: C/D layout col=lane&15, row=(lane>>4)*4+reg
  #pragma unroll
  for (int mi = 0; mi < 4; ++mi){
    int row = m0 + wr*64 + mi*16 + g*4;
    #pragma unroll
    for (int ni = 0; ni < 4; ++ni){
      int col = n0 + wc*64 + ni*16 + lo;
      float bv = bias[col];
      #pragma unroll
      for (int j = 0; j < 4; ++j){
        float v = acc[mi][ni][j] + bv;
        if (OUT_BF16) ((u16*)Cout)[(size_t)(row + j) * N + col] = f2bf(v);
        else          ((float*)Cout)[(size_t)(row + j) * N + col] = v;
      }
    }
  }
}

// ---------------- RoPE + split qkv -> q,k,v in [B][H][S][DH] bf16 ----------------
__global__ __launch_bounds__(256) void rope_split(const u16* __restrict__ qkv,
    u16* __restrict__ qb, u16* __restrict__ kb, u16* __restrict__ vb){
  int idx = blockIdx.x * 256 + threadIdx.x;   // B*S*H*32 = 2097152 threads
  int m = idx >> 9;           // b*S + s
  int rem = idx & 511;
  int h = rem >> 5;
  int i = rem & 31;
  int b = m >> 10;
  int s = m & 1023;
  size_t base = (size_t)m * 3072 + h * 64 + i;
  float q1 = bf2f(qkv[base]),        q2 = bf2f(qkv[base + 32]);
  float k1 = bf2f(qkv[base + 1024]), k2 = bf2f(qkv[base + 1024 + 32]);
  u16  v1 = qkv[base + 2048],        v2 = qkv[base + 2048 + 32];
  float invf = powf(10000.0f, -(float)i * (1.0f / 32.0f));
  float ang = (float)s * invf;
  float sn, cs;
  sincosf(ang, &sn, &cs);
  size_t dst = ((size_t)(b * H_ + h) * S_ + s) * DH_ + i;
  qb[dst]      = f2bf(q1 * cs - q2 * sn);
  qb[dst + 32] = f2bf(q2 * cs + q1 * sn);
  kb[dst]      = f2bf(k1 * cs - k2 * sn);
  kb[dst + 32] = f2bf(k2 * cs + k1 * sn);
  vb[dst]      = v1;
  vb[dst + 32] = v2;
}

// ---------------- causal flash attention ----------------
// grid (B*H, S/64); block 256 = 4 waves; wave w owns 16 q-rows.
__global__ __launch_bounds__(256) void attn_fwd(const u16* __restrict__ qb,
    const u16* __restrict__ kb, const u16* __restrict__ vb,
    u16* __restrict__ ctx){
  const int bh = blockIdx.x;
  const int qt = blockIdx.y;
  const int b = bh >> 4, h = bh & 15;
  const int tid = threadIdx.x;
  const int lane = tid & 63, w = tid >> 6;
  const int lo = lane & 15, g = lane >> 4;

  __shared__ u16 Klds[64][72];        // K tile, row-major [kv][d], +8 pad
  __shared__ u16 Vt[64][72];          // V tile transposed [d][kv]
  __shared__ u16 Plds[4][16][72];     // per-wave P bounce [qrow][kv]

  bf16x8 qf[2];
  {
    const u16* qptr = qb + ((size_t)bh * S_ + qt*64 + w*16 + lo) * DH_ + g*8;
    qf[0] = *(const bf16x8*)(qptr);
    qf[1] = *(const bf16x8*)(qptr + 32);
  }

  float m_run[4], l_run[4];
  f32x4 O[4];
  #pragma unroll
  for (int j = 0; j < 4; ++j){ m_run[j] = -1e30f; l_run[j] = 0.f; }
  #pragma unroll
  for (int c = 0; c < 4; ++c) O[c] = (f32x4){0.f, 0.f, 0.f, 0.f};

  for (int kt = 0; kt <= qt; ++kt){
    __syncthreads();   // protect LDS from previous iteration's readers
    const u16* ksrc = kb + ((size_t)bh * S_ + kt*64) * DH_;
    const u16* vsrc = vb + ((size_t)bh * S_ + kt*64) * DH_;
    #pragma unroll
    for (int it = 0; it < 2; ++it){
      int chunk = tid + it * 256;   // 0..511
      int row = chunk >> 3;         // 64 rows
      int c0 = (chunk & 7) * 8;
      *(bf16x8*)(&Klds[row][c0]) = *(const bf16x8*)(ksrc + row * DH_ + c0);
      bf16x8 vv = *(const bf16x8*)(vsrc + row * DH_ + c0);
      #pragma unroll
      for (int j2 = 0; j2 < 8; ++j2) Vt[c0 + j2][row] = (u16)vv[j2];
    }
    __syncthreads();

    // scores: S = Q (16x64) x K^T (64x64) per wave -> 4 col-frags
    f32x4 sacc[4];
    #pragma unroll
    for (int c = 0; c < 4; ++c) sacc[c] = (f32x4){0.f, 0.f, 0.f, 0.f};
    #pragma unroll
    for (int cf = 0; cf < 4; ++cf){
      #pragma unroll
      for (int ks = 0; ks < 2; ++ks){
        bf16x8 kf = *(const bf16x8*)(&Klds[cf*16 + lo][ks*32 + g*8]);
        sacc[cf] = __builtin_amdgcn_mfma_f32_16x16x32_bf16(qf[ks], kf, sacc[cf], 0, 0, 0);
      }
    }
    // scale + causal mask (reference adds -10000, not -inf)
    // wave w owns q-rows w*16 + (g*4+j) within the 64-row tile  <-- fixed
    #pragma unroll
    for (int cf = 0; cf < 4; ++cf){
      #pragma unroll
      for (int j = 0; j < 4; ++j){
        float s = sacc[cf][j] * 0.125f;
        if (kt == qt){
          int kj = cf*16 + lo;
          int qr = w*16 + g*4 + j;
          if (kj > qr) s -= 10000.f;
        }
        sacc[cf][j] = s;
      }
    }
    // online softmax: rows r = g*4+j live across 16 lanes (lane&15)
    float mnew[4], alpha[4], rsum[4];
    #pragma unroll
    for (int j = 0; j < 4; ++j){
      float v = fmaxf(fmaxf(sacc[0][j], sacc[1][j]), fmaxf(sacc[2][j], sacc[3][j]));
      v = fmaxf(v, __shfl_xor(v, 1));
      v = fmaxf(v, __shfl_xor(v, 2));
      v = fmaxf(v, __shfl_xor(v, 4));
      v = fmaxf(v, __shfl_xor(v, 8));
      mnew[j] = fmaxf(m_run[j], v);
      alpha[j] = __expf(m_run[j] - mnew[j]);
      m_run[j] = mnew[j];
      rsum[j] = 0.f;
    }
    #pragma unroll
    for (int cf = 0; cf < 4; ++cf){
      #pragma unroll
      for (int j = 0; j < 4; ++j){
        float p = __expf(sacc[cf][j] - mnew[j]);
        sacc[cf][j] = p;
        rsum[j] += p;
      }
    }
    #pragma unroll
    for (int j = 0; j < 4; ++j){
      float v = rsum[j];
      v += __shfl_xor(v, 1);
      v += __shfl_xor(v, 2);
      v += __shfl_xor(v, 4);
      v += __shfl_xor(v, 8);
      l_run[j] = l_run[j] * alpha[j] + v;
    }
    #pragma unroll
    for (int c = 0; c < 4; ++c)
      #pragma unroll
      for (int j = 0; j < 4; ++j) O[c][j] *= alpha[j];

    // bounce P through LDS into A-fragment layout (wave-local)
    #pragma unroll
    for (int cf = 0; cf < 4; ++cf)
      #pragma unroll
      for (int j = 0; j < 4; ++j)
        Plds[w][g*4 + j][cf*16 + lo] = f2bf(sacc[cf][j]);

    // PV: O (16x64) += P (16x64) x V (64x64)
    #pragma unroll
    for (int ks = 0; ks < 2; ++ks){
      bf16x8 pf = *(const bf16x8*)(&Plds[w][lo][ks*32 + g*8]);
      #pragma unroll
      for (int ocf = 0; ocf < 4; ++ocf){
        bf16x8 vf = *(const bf16x8*)(&Vt[ocf*16 + lo][ks*32 + g*8]);
        O[ocf] = __builtin_amdgcn_mfma_f32_16x16x32_bf16(pf, vf, O[ocf], 0, 0, 0);
      }
    }
  }

  float inv[4];
  #pragma unroll
  for (int j = 0; j < 4; ++j) inv[j] = 1.0f / l_run[j];
  #pragma unroll
  for (int ocf = 0; ocf < 4; ++ocf){
    #pragma unroll
    for (int j = 0; j < 4; ++j){
      int qi = qt*64 + w*16 + g*4 + j;
      int d = ocf*16 + lo;
      ctx[((size_t)(b * S_ + qi)) * D_ + h * DH_ + d] = f2bf(O[ocf][j] * inv[j]);
    }
  }
}

// ---------------- launch ----------------
extern "C" void kernel_launch(void* const* d_in, const int* in_sizes, int n_in,
                              void* d_out, int out_size, void* d_ws, size_t ws_size,
                              hipStream_t stream){
  (void)in_sizes; (void)n_in; (void)out_size; (void)ws_size;
  const float* x    = (const float*)d_in[0];
  const float* Wqkv = (const float*)d_in[1];
  const float* bqkv = (const float*)d_in[2];
  const float* Wout = (const float*)d_in[3];
  const float* bout = (const float*)d_in[4];
  float* out = (float*)d_out;

  char* p = (char*)d_ws;
  u16* qkv_bf  = (u16*)p; p += (size_t)4096*3072*2;
  u16* x_bf    = (u16*)p; p += (size_t)4096*1024*2;
  u16* wqkv_bf = (u16*)p; p += (size_t)3072*1024*2;
  u16* wout_bf = (u16*)p; p += (size_t)1024*1024*2;
  u16* q_bf    = (u16*)p; p += (size_t)4096*1024*2;
  u16* k_bf    = (u16*)p; p += (size_t)4096*1024*2;
  u16* v_bf    = (u16*)p; p += (size_t)4096*1024*2;
  u16* ctx_bf  = (u16*)p; p += (size_t)4096*1024*2;

  cast_bf16<<<4096, 256, 0, stream>>>(x, x_bf, 4096*1024);
  cast_bf16<<<3072, 256, 0, stream>>>(Wqkv, wqkv_bf, 3072*1024);
  cast_bf16<<<1024, 256, 0, stream>>>(Wout, wout_bf, 1024*1024);

  gemm_bt<1><<<dim3(32, 24), 256, 0, stream>>>(x_bf, wqkv_bf, bqkv, qkv_bf, 4096, 3072, 1024);

  rope_split<<<8192, 256, 0, stream>>>(qkv_bf, q_bf, k_bf, v_bf);

  attn_fwd<<<dim3(64, 16), 256, 0, stream>>>(q_bf, k_bf, v_bf, ctx_bf);

  gemm_bt<0><<<dim3(32, 8), 256, 0, stream>>>(ctx_bf, wout_bf, bout, out, 4096, 1024, 1024);
}

// Round 4
// 135.209 us; speedup vs baseline: 1.0621x; 1.0621x over previous
//
#include <hip/hip_runtime.h>

#define B_ 4
#define S_ 1024
#define D_ 1024
#define H_ 16
#define DH_ 64

typedef unsigned short u16;
typedef __attribute__((ext_vector_type(8))) short bf16x8;
typedef __attribute__((ext_vector_type(4))) float f32x4;

__device__ __forceinline__ float bf2f(u16 h){
  union { unsigned u; float f; } x; x.u = ((unsigned)h) << 16; return x.f;
}
__device__ __forceinline__ u16 f2bf(float f){
  union { float f; unsigned u; } x; x.f = f;
  unsigned u = x.u;
  return (u16)((u + 0x7fffu + ((u >> 16) & 1u)) >> 16);
}

__device__ __forceinline__ void gload16(const u16* g, u16* l){
  __builtin_amdgcn_global_load_lds(
      (const __attribute__((address_space(1))) unsigned int*)g,
      (__attribute__((address_space(3))) unsigned int*)l, 16, 0, 0);
}

// ---------------- cast fp32 -> bf16 (n % 4 == 0) ----------------
__global__ __launch_bounds__(256) void cast_bf16(const float* __restrict__ in,
                                                 u16* __restrict__ out, int n){
  int i = (blockIdx.x * 256 + threadIdx.x) * 4;
  if (i >= n) return;
  float4 v = *(const float4*)(in + i);
  union { u16 s[4]; uint2 u; } o;
  o.s[0] = f2bf(v.x); o.s[1] = f2bf(v.y); o.s[2] = f2bf(v.z); o.s[3] = f2bf(v.w);
  *(uint2*)(out + i) = o.u;
}

// ---------------- GEMM: C[m][n] = sum_k A[m][k]*Bm[n][k] + bias[n] ----------------
template<int OUT_BF16>
__global__ __launch_bounds__(256) void gemm_bt(const u16* __restrict__ A,
    const u16* __restrict__ Bm, const float* __restrict__ bias,
    void* __restrict__ Cout, int M, int N, int K){
  __shared__ u16 As[2][128*32];
  __shared__ u16 Bs[2][128*32];
  const int tid = threadIdx.x;
  const int lane = tid & 63;
  const int w = tid >> 6;
  const int wr = w >> 1, wc = w & 1;
  const int lo = lane & 15, g = lane >> 4;
  const int m0 = blockIdx.x * 128, n0 = blockIdx.y * 128;

  f32x4 acc[4][4];
  #pragma unroll
  for (int i = 0; i < 4; ++i)
    #pragma unroll
    for (int j = 0; j < 4; ++j) acc[i][j] = (f32x4){0.f, 0.f, 0.f, 0.f};

  const int nt = K >> 5;

  auto stage = [&](int buf, int kt){
    const u16* ga = A + (size_t)m0 * K + kt * 32;
    const u16* gb = Bm + (size_t)n0 * K + kt * 32;
    #pragma unroll
    for (int it = 0; it < 2; ++it){
      int chunk = tid + it * 256;       // 0..511
      int row = chunk >> 2;             // 128 rows
      int c0 = (chunk & 3) * 8;         // 4 chunks of 8 bf16 per row
      gload16(ga + (size_t)row * K + c0, &As[buf][chunk * 8]);
      gload16(gb + (size_t)row * K + c0, &Bs[buf][chunk * 8]);
    }
  };

  stage(0, 0);
  __syncthreads();
  int buf = 0;
  for (int kt = 0; kt < nt; ++kt){
    if (kt + 1 < nt) stage(buf ^ 1, kt + 1);
    bf16x8 af[4], bfr[4];
    #pragma unroll
    for (int mi = 0; mi < 4; ++mi)
      af[mi] = *(const bf16x8*)(&As[buf][(wr*64 + mi*16 + lo)*32 + g*8]);
    #pragma unroll
    for (int ni = 0; ni < 4; ++ni)
      bfr[ni] = *(const bf16x8*)(&Bs[buf][(wc*64 + ni*16 + lo)*32 + g*8]);
    #pragma unroll
    for (int mi = 0; mi < 4; ++mi)
      #pragma unroll
      for (int ni = 0; ni < 4; ++ni)
        acc[mi][ni] = __builtin_amdgcn_mfma_f32_16x16x32_bf16(af[mi], bfr[ni], acc[mi][ni], 0, 0, 0);
    __syncthreads();
    buf ^= 1;
  }

  #pragma unroll
  for (int mi = 0; mi < 4; ++mi){
    int row = m0 + wr*64 + mi*16 + g*4;
    #pragma unroll
    for (int ni = 0; ni < 4; ++ni){
      int col = n0 + wc*64 + ni*16 + lo;
      float bv = bias[col];
      #pragma unroll
      for (int j = 0; j < 4; ++j){
        float v = acc[mi][ni][j] + bv;
        if (OUT_BF16) ((u16*)Cout)[(size_t)(row + j) * N + col] = f2bf(v);
        else          ((float*)Cout)[(size_t)(row + j) * N + col] = v;
      }
    }
  }
}

// ---------------- RoPE + split qkv -> q,k [bh][s][d]; v TRANSPOSED [bh][d][s] ----------------
__global__ __launch_bounds__(256) void rope_split(const u16* __restrict__ qkv,
    u16* __restrict__ qb, u16* __restrict__ kb, u16* __restrict__ vtb){
  int idx = blockIdx.x * 256 + threadIdx.x;   // B*S*H*32 = 2097152 threads
  int m = idx >> 9;           // b*S + s
  int rem = idx & 511;
  int h = rem >> 5;
  int i = rem & 31;
  int b = m >> 10;
  int s = m & 1023;
  size_t base = (size_t)m * 3072 + h * 64 + i;
  float q1 = bf2f(qkv[base]),        q2 = bf2f(qkv[base + 32]);
  float k1 = bf2f(qkv[base + 1024]), k2 = bf2f(qkv[base + 1024 + 32]);
  u16  v1 = qkv[base + 2048],        v2 = qkv[base + 2048 + 32];
  float invf = powf(10000.0f, -(float)i * (1.0f / 32.0f));
  float ang = (float)s * invf;
  float sn, cs;
  sincosf(ang, &sn, &cs);
  int bh = b * H_ + h;
  size_t dst = ((size_t)bh * S_ + s) * DH_ + i;
  qb[dst]      = f2bf(q1 * cs - q2 * sn);
  qb[dst + 32] = f2bf(q2 * cs + q1 * sn);
  kb[dst]      = f2bf(k1 * cs - k2 * sn);
  kb[dst + 32] = f2bf(k2 * cs + k1 * sn);
  // V transposed: [bh][d][s]
  vtb[((size_t)bh * DH_ + i) * S_ + s]      = v1;
  vtb[((size_t)bh * DH_ + i + 32) * S_ + s] = v2;
}

// ---------------- causal flash attention, work-balanced fused pairs ----------------
// grid (64 bh, 8 p); block 256 = 4 waves. Block handles q-tiles {p, 15-p},
// sharing each staged K/V tile. Exactly 17 compute-tile-steps per block.
// K and V^T tiles staged via global_load_lds, XOR-swizzled via pre-swizzled
// global source column (both-sides rule): LDS(row,cb) = G(row, cb^((row&7)<<4)).
__global__ __launch_bounds__(256) void attn_fwd(const u16* __restrict__ qb,
    const u16* __restrict__ kb, const u16* __restrict__ vtb,
    u16* __restrict__ ctx){
  const int bh = blockIdx.x;
  const int p  = blockIdx.y;
  const int qtA = p, qtB = 15 - p;
  const int b = bh >> 4, h = bh & 15;
  const int tid = threadIdx.x;
  const int lane = tid & 63, w = tid >> 6;
  const int lo = lane & 15, g = lane >> 4;

  __shared__ u16 Kl[2][64*64];        // K tile [kv][d], XOR-swizzled rows
  __shared__ u16 Vl[2][64*64];        // V^T tile [d][kv], XOR-swizzled rows
  __shared__ u16 Plds[4][16][72];     // per-wave P bounce [qrow][kv], +8 pad

  // Q fragments for both tiles
  bf16x8 qfA[2], qfB[2];
  {
    const u16* qa = qb + ((size_t)bh * S_ + qtA*64 + w*16 + lo) * DH_ + g*8;
    qfA[0] = *(const bf16x8*)(qa);  qfA[1] = *(const bf16x8*)(qa + 32);
    const u16* qe = qb + ((size_t)bh * S_ + qtB*64 + w*16 + lo) * DH_ + g*8;
    qfB[0] = *(const bf16x8*)(qe);  qfB[1] = *(const bf16x8*)(qe + 32);
  }

  float mA[4], lA[4], mB[4], lB[4];
  f32x4 OA[4], OB[4];
  #pragma unroll
  for (int j = 0; j < 4; ++j){ mA[j] = -1e30f; lA[j] = 0.f; mB[j] = -1e30f; lB[j] = 0.f; }
  #pragma unroll
  for (int c = 0; c < 4; ++c){ OA[c] = (f32x4){0.f,0.f,0.f,0.f}; OB[c] = (f32x4){0.f,0.f,0.f,0.f}; }

  // staging: each K/V tile is 64 rows x 128B = 8KB = 512 chunks of 16B.
  // 256 threads x 2 iterations, LDS dest linear in chunk order, global source
  // column inverse-swizzled.
  auto stage = [&](int buf, int kt){
    const u16* ksrc = kb  + ((size_t)bh * S_ + kt*64) * DH_;
    const u16* vsrc = vtb + (size_t)bh * DH_ * S_ + kt*64;
    #pragma unroll
    for (int it = 0; it < 2; ++it){
      int c = tid + it * 256;               // 0..511
      int row = c >> 3;                     // 64 rows
      int colb = (c & 7) * 16;              // byte col 0..112
      int colbs = colb ^ ((row & 7) << 4);  // inverse-swizzled byte col
      gload16(ksrc + (size_t)row * DH_ + (colbs >> 1), &Kl[buf][c * 8]);
      gload16(vsrc + (size_t)row * S_  + (colbs >> 1), &Vl[buf][c * 8]);
    }
  };

  int buf = 0;

  auto computeTile = [&](const bf16x8* qf, f32x4* O, float* m_run, float* l_run,
                         bool diag){
    f32x4 sacc[4];
    #pragma unroll
    for (int c = 0; c < 4; ++c) sacc[c] = (f32x4){0.f,0.f,0.f,0.f};
    #pragma unroll
    for (int cf = 0; cf < 4; ++cf){
      int r = cf*16 + lo;
      #pragma unroll
      for (int ks = 0; ks < 2; ++ks){
        int byteoff = r*128 + ((ks*64 + g*16) ^ ((lo & 7) << 4));
        bf16x8 kf = *(const bf16x8*)(&Kl[buf][byteoff >> 1]);
        sacc[cf] = __builtin_amdgcn_mfma_f32_16x16x32_bf16(qf[ks], kf, sacc[cf], 0, 0, 0);
      }
    }
    #pragma unroll
    for (int cf = 0; cf < 4; ++cf){
      #pragma unroll
      for (int j = 0; j < 4; ++j){
        float s = sacc[cf][j] * 0.125f;
        if (diag){
          int kj = cf*16 + lo;
          int qr = w*16 + g*4 + j;
          if (kj > qr) s -= 10000.f;
        }
        sacc[cf][j] = s;
      }
    }
    float mnew[4], alpha[4], rsum[4];
    #pragma unroll
    for (int j = 0; j < 4; ++j){
      float v = fmaxf(fmaxf(sacc[0][j], sacc[1][j]), fmaxf(sacc[2][j], sacc[3][j]));
      v = fmaxf(v, __shfl_xor(v, 1));
      v = fmaxf(v, __shfl_xor(v, 2));
      v = fmaxf(v, __shfl_xor(v, 4));
      v = fmaxf(v, __shfl_xor(v, 8));
      mnew[j] = fmaxf(m_run[j], v);
      alpha[j] = __expf(m_run[j] - mnew[j]);
      m_run[j] = mnew[j];
      rsum[j] = 0.f;
    }
    #pragma unroll
    for (int cf = 0; cf < 4; ++cf){
      #pragma unroll
      for (int j = 0; j < 4; ++j){
        float pv = __expf(sacc[cf][j] - mnew[j]);
        sacc[cf][j] = pv;
        rsum[j] += pv;
      }
    }
    #pragma unroll
    for (int j = 0; j < 4; ++j){
      float v = rsum[j];
      v += __shfl_xor(v, 1);
      v += __shfl_xor(v, 2);
      v += __shfl_xor(v, 4);
      v += __shfl_xor(v, 8);
      l_run[j] = l_run[j] * alpha[j] + v;
    }
    #pragma unroll
    for (int c = 0; c < 4; ++c)
      #pragma unroll
      for (int j = 0; j < 4; ++j) O[c][j] *= alpha[j];

    #pragma unroll
    for (int cf = 0; cf < 4; ++cf)
      #pragma unroll
      for (int j = 0; j < 4; ++j)
        Plds[w][g*4 + j][cf*16 + lo] = f2bf(sacc[cf][j]);

    #pragma unroll
    for (int ks = 0; ks < 2; ++ks){
      bf16x8 pf = *(const bf16x8*)(&Plds[w][lo][ks*32 + g*8]);
      #pragma unroll
      for (int ocf = 0; ocf < 4; ++ocf){
        int r = ocf*16 + lo;
        int byteoff = r*128 + ((ks*64 + g*16) ^ ((lo & 7) << 4));
        bf16x8 vf = *(const bf16x8*)(&Vl[buf][byteoff >> 1]);
        O[ocf] = __builtin_amdgcn_mfma_f32_16x16x32_bf16(pf, vf, O[ocf], 0, 0, 0);
      }
    }
  };

  stage(0, 0);
  for (int kt = 0; kt <= qtB; ++kt){
    __syncthreads();                       // staged loads drained; LDS safe
    if (kt < qtB) stage(buf ^ 1, kt + 1);  // async prefetch overlaps compute
    if (kt <= qtA) computeTile(qfA, OA, mA, lA, kt == qtA);
    computeTile(qfB, OB, mB, lB, kt == qtB);
    buf ^= 1;
  }

  float invA[4], invB[4];
  #pragma unroll
  for (int j = 0; j < 4; ++j){ invA[j] = 1.0f / lA[j]; invB[j] = 1.0f / lB[j]; }
  #pragma unroll
  for (int ocf = 0; ocf < 4; ++ocf){
    #pragma unroll
    for (int j = 0; j < 4; ++j){
      int d = ocf*16 + lo;
      int qiA = qtA*64 + w*16 + g*4 + j;
      ctx[((size_t)(b * S_ + qiA)) * D_ + h * DH_ + d] = f2bf(OA[ocf][j] * invA[j]);
      int qiB = qtB*64 + w*16 + g*4 + j;
      ctx[((size_t)(b * S_ + qiB)) * D_ + h * DH_ + d] = f2bf(OB[ocf][j] * invB[j]);
    }
  }
}

// ---------------- launch ----------------
extern "C" void kernel_launch(void* const* d_in, const int* in_sizes, int n_in,
                              void* d_out, int out_size, void* d_ws, size_t ws_size,
                              hipStream_t stream){
  (void)in_sizes; (void)n_in; (void)out_size; (void)ws_size;
  const float* x    = (const float*)d_in[0];
  const float* Wqkv = (const float*)d_in[1];
  const float* bqkv = (const float*)d_in[2];
  const float* Wout = (const float*)d_in[3];
  const float* bout = (const float*)d_in[4];
  float* out = (float*)d_out;

  char* p = (char*)d_ws;
  u16* qkv_bf  = (u16*)p; p += (size_t)4096*3072*2;
  u16* x_bf    = (u16*)p; p += (size_t)4096*1024*2;
  u16* wqkv_bf = (u16*)p; p += (size_t)3072*1024*2;
  u16* wout_bf = (u16*)p; p += (size_t)1024*1024*2;
  u16* q_bf    = (u16*)p; p += (size_t)4096*1024*2;
  u16* k_bf    = (u16*)p; p += (size_t)4096*1024*2;
  u16* vt_bf   = (u16*)p; p += (size_t)4096*1024*2;
  u16* ctx_bf  = (u16*)p; p += (size_t)4096*1024*2;

  cast_bf16<<<4096, 256, 0, stream>>>(x, x_bf, 4096*1024);
  cast_bf16<<<3072, 256, 0, stream>>>(Wqkv, wqkv_bf, 3072*1024);
  cast_bf16<<<1024, 256, 0, stream>>>(Wout, wout_bf, 1024*1024);

  gemm_bt<1><<<dim3(32, 24), 256, 0, stream>>>(x_bf, wqkv_bf, bqkv, qkv_bf, 4096, 3072, 1024);

  rope_split<<<8192, 256, 0, stream>>>(qkv_bf, q_bf, k_bf, vt_bf);

  attn_fwd<<<dim3(64, 8), 256, 0, stream>>>(q_bf, k_bf, vt_bf, ctx_bf);

  gemm_bt<0><<<dim3(32, 8), 256, 0, stream>>>(ctx_bf, wout_bf, bout, out, 4096, 1024, 1024);
}

// Round 5
// 122.912 us; speedup vs baseline: 1.1684x; 1.1000x over previous
//
#include <hip/hip_runtime.h>

#define B_ 4
#define S_ 1024
#define D_ 1024
#define H_ 16
#define DH_ 64

typedef unsigned short u16;
typedef __attribute__((ext_vector_type(8))) short bf16x8;
typedef __attribute__((ext_vector_type(4))) float f32x4;

__device__ __forceinline__ float bf2f(u16 h){
  union { unsigned u; float f; } x; x.u = ((unsigned)h) << 16; return x.f;
}
__device__ __forceinline__ u16 f2bf(float f){
  union { float f; unsigned u; } x; x.f = f;
  unsigned u = x.u;
  return (u16)((u + 0x7fffu + ((u >> 16) & 1u)) >> 16);
}

__device__ __forceinline__ void gload16(const u16* g, u16* l){
  __builtin_amdgcn_global_load_lds(
      (const __attribute__((address_space(1))) unsigned int*)g,
      (__attribute__((address_space(3))) unsigned int*)l, 16, 0, 0);
}

// ---------------- cast fp32 -> bf16 (n % 4 == 0) ----------------
__global__ __launch_bounds__(256) void cast_bf16(const float* __restrict__ in,
                                                 u16* __restrict__ out, int n){
  int i = (blockIdx.x * 256 + threadIdx.x) * 4;
  if (i >= n) return;
  float4 v = *(const float4*)(in + i);
  union { u16 s[4]; uint2 u; } o;
  o.s[0] = f2bf(v.x); o.s[1] = f2bf(v.y); o.s[2] = f2bf(v.z); o.s[3] = f2bf(v.w);
  *(uint2*)(out + i) = o.u;
}

// ---------------- GEMM: C[m][n] = sum_k A[m][k]*Bm[n][k] + bias[n] ----------------
template<int OUT_BF16>
__global__ __launch_bounds__(256) void gemm_bt(const u16* __restrict__ A,
    const u16* __restrict__ Bm, const float* __restrict__ bias,
    void* __restrict__ Cout, int M, int N, int K){
  __shared__ u16 As[2][128*32];
  __shared__ u16 Bs[2][128*32];
  const int tid = threadIdx.x;
  const int lane = tid & 63;
  const int w = tid >> 6;
  const int wr = w >> 1, wc = w & 1;
  const int lo = lane & 15, g = lane >> 4;
  const int m0 = blockIdx.x * 128, n0 = blockIdx.y * 128;

  f32x4 acc[4][4];
  #pragma unroll
  for (int i = 0; i < 4; ++i)
    #pragma unroll
    for (int j = 0; j < 4; ++j) acc[i][j] = (f32x4){0.f, 0.f, 0.f, 0.f};

  const int nt = K >> 5;

  auto stage = [&](int buf, int kt){
    const u16* ga = A + (size_t)m0 * K + kt * 32;
    const u16* gb = Bm + (size_t)n0 * K + kt * 32;
    #pragma unroll
    for (int it = 0; it < 2; ++it){
      int chunk = tid + it * 256;       // 0..511
      int row = chunk >> 2;             // 128 rows
      int c0 = (chunk & 3) * 8;         // 4 chunks of 8 bf16 per row
      gload16(ga + (size_t)row * K + c0, &As[buf][chunk * 8]);
      gload16(gb + (size_t)row * K + c0, &Bs[buf][chunk * 8]);
    }
  };

  stage(0, 0);
  __syncthreads();
  int buf = 0;
  for (int kt = 0; kt < nt; ++kt){
    if (kt + 1 < nt) stage(buf ^ 1, kt + 1);
    bf16x8 af[4], bfr[4];
    #pragma unroll
    for (int mi = 0; mi < 4; ++mi)
      af[mi] = *(const bf16x8*)(&As[buf][(wr*64 + mi*16 + lo)*32 + g*8]);
    #pragma unroll
    for (int ni = 0; ni < 4; ++ni)
      bfr[ni] = *(const bf16x8*)(&Bs[buf][(wc*64 + ni*16 + lo)*32 + g*8]);
    #pragma unroll
    for (int mi = 0; mi < 4; ++mi)
      #pragma unroll
      for (int ni = 0; ni < 4; ++ni)
        acc[mi][ni] = __builtin_amdgcn_mfma_f32_16x16x32_bf16(af[mi], bfr[ni], acc[mi][ni], 0, 0, 0);
    __syncthreads();
    buf ^= 1;
  }

  #pragma unroll
  for (int mi = 0; mi < 4; ++mi){
    int row = m0 + wr*64 + mi*16 + g*4;
    #pragma unroll
    for (int ni = 0; ni < 4; ++ni){
      int col = n0 + wc*64 + ni*16 + lo;
      float bv = bias[col];
      #pragma unroll
      for (int j = 0; j < 4; ++j){
        float v = acc[mi][ni][j] + bv;
        if (OUT_BF16) ((u16*)Cout)[(size_t)(row + j) * N + col] = f2bf(v);
        else          ((float*)Cout)[(size_t)(row + j) * N + col] = v;
      }
    }
  }
}

// ---------------- RoPE + split, LDS-tiled V transpose ----------------
// grid (bh=64, st=16); block 256. Each block: head h of batch b, 64 seq rows.
// q,k: rotate + coalesced store to [bh][s][d]. v: LDS 64x64 transpose,
// coalesced store to [bh][d][s].
__global__ __launch_bounds__(256) void rope_split(const u16* __restrict__ qkv,
    u16* __restrict__ qb, u16* __restrict__ kb, u16* __restrict__ vtb){
  const int bh = blockIdx.x;
  const int st = blockIdx.y;
  const int b = bh >> 4, h = bh & 15;
  const int t = threadIdx.x;
  const int sl = t >> 2;          // 0..63 local seq
  const int c4 = t & 3;
  const int i0 = c4 * 8;          // 0,8,16,24

  __shared__ u16 Vlds[64][72];

  const int s = st * 64 + sl;
  const int m = b * S_ + s;
  const u16* src = qkv + (size_t)m * 3072 + h * 64;

  bf16x8 q1v = *(const bf16x8*)(src + i0);
  bf16x8 q2v = *(const bf16x8*)(src + i0 + 32);
  bf16x8 k1v = *(const bf16x8*)(src + 1024 + i0);
  bf16x8 k2v = *(const bf16x8*)(src + 1024 + i0 + 32);
  bf16x8 v1v = *(const bf16x8*)(src + 2048 + i0);
  bf16x8 v2v = *(const bf16x8*)(src + 2048 + i0 + 32);

  bf16x8 qo1, qo2, ko1, ko2;
  #pragma unroll
  for (int e = 0; e < 8; ++e){
    int i = i0 + e;
    float invf = powf(10000.0f, -(float)i * (1.0f / 32.0f));
    float ang = (float)s * invf;
    float sn, cs;
    sincosf(ang, &sn, &cs);
    float q1 = bf2f((u16)q1v[e]), q2 = bf2f((u16)q2v[e]);
    float k1 = bf2f((u16)k1v[e]), k2 = bf2f((u16)k2v[e]);
    qo1[e] = (short)f2bf(q1 * cs - q2 * sn);
    qo2[e] = (short)f2bf(q2 * cs + q1 * sn);
    ko1[e] = (short)f2bf(k1 * cs - k2 * sn);
    ko2[e] = (short)f2bf(k2 * cs + k1 * sn);
    Vlds[i][sl]      = (u16)v1v[e];
    Vlds[i + 32][sl] = (u16)v2v[e];
  }

  size_t dst = ((size_t)bh * S_ + s) * DH_ + i0;
  *(bf16x8*)(qb + dst)      = qo1;
  *(bf16x8*)(qb + dst + 32) = qo2;
  *(bf16x8*)(kb + dst)      = ko1;
  *(bf16x8*)(kb + dst + 32) = ko2;

  __syncthreads();

  // writeout V^T: thread t -> d = t>>2, 16 s-elems at (t&3)*16
  const int d = t >> 2;
  const int sc = (t & 3) * 16;
  bf16x8 a = *(const bf16x8*)(&Vlds[d][sc]);
  bf16x8 c = *(const bf16x8*)(&Vlds[d][sc + 8]);
  size_t vdst = ((size_t)bh * DH_ + d) * S_ + st * 64 + sc;
  *(bf16x8*)(vtb + vdst)     = a;
  *(bf16x8*)(vtb + vdst + 8) = c;
}

// ---------------- causal flash attention, un-paired for occupancy ----------------
// grid (64 bh, 16); block 256 = 4 waves; qt = 15 - blockIdx.y (longest first).
// K and V^T tiles staged via global_load_lds, XOR-swizzled via pre-swizzled
// global source column (both-sides rule): LDS(row,cb) = G(row, cb^((row&7)<<4)).
__global__ __launch_bounds__(256) void attn_fwd(const u16* __restrict__ qb,
    const u16* __restrict__ kb, const u16* __restrict__ vtb,
    u16* __restrict__ ctx){
  const int bh = blockIdx.x;
  const int qt = 15 - blockIdx.y;       // longest blocks dispatched first
  const int b = bh >> 4, h = bh & 15;
  const int tid = threadIdx.x;
  const int lane = tid & 63, w = tid >> 6;
  const int lo = lane & 15, g = lane >> 4;

  __shared__ u16 Kl[2][64*64];        // K tile [kv][d], XOR-swizzled rows
  __shared__ u16 Vl[2][64*64];        // V^T tile [d][kv], XOR-swizzled rows
  __shared__ u16 Plds[4][16][72];     // per-wave P bounce [qrow][kv], +8 pad

  bf16x8 qf[2];
  {
    const u16* qa = qb + ((size_t)bh * S_ + qt*64 + w*16 + lo) * DH_ + g*8;
    qf[0] = *(const bf16x8*)(qa);  qf[1] = *(const bf16x8*)(qa + 32);
  }

  float m_run[4], l_run[4];
  f32x4 O[4];
  #pragma unroll
  for (int j = 0; j < 4; ++j){ m_run[j] = -1e30f; l_run[j] = 0.f; }
  #pragma unroll
  for (int c = 0; c < 4; ++c) O[c] = (f32x4){0.f,0.f,0.f,0.f};

  // staging: each K/V tile is 64 rows x 128B = 8KB = 512 chunks of 16B.
  auto stage = [&](int buf, int kt){
    const u16* ksrc = kb  + ((size_t)bh * S_ + kt*64) * DH_;
    const u16* vsrc = vtb + (size_t)bh * DH_ * S_ + kt*64;
    #pragma unroll
    for (int it = 0; it < 2; ++it){
      int c = tid + it * 256;               // 0..511
      int row = c >> 3;                     // 64 rows
      int colb = (c & 7) * 16;              // byte col 0..112
      int colbs = colb ^ ((row & 7) << 4);  // inverse-swizzled byte col
      gload16(ksrc + (size_t)row * DH_ + (colbs >> 1), &Kl[buf][c * 8]);
      gload16(vsrc + (size_t)row * S_  + (colbs >> 1), &Vl[buf][c * 8]);
    }
  };

  int buf = 0;

  auto computeTile = [&](bool diag){
    f32x4 sacc[4];
    #pragma unroll
    for (int c = 0; c < 4; ++c) sacc[c] = (f32x4){0.f,0.f,0.f,0.f};
    #pragma unroll
    for (int cf = 0; cf < 4; ++cf){
      int r = cf*16 + lo;
      #pragma unroll
      for (int ks = 0; ks < 2; ++ks){
        int byteoff = r*128 + ((ks*64 + g*16) ^ ((lo & 7) << 4));
        bf16x8 kf = *(const bf16x8*)(&Kl[buf][byteoff >> 1]);
        sacc[cf] = __builtin_amdgcn_mfma_f32_16x16x32_bf16(qf[ks], kf, sacc[cf], 0, 0, 0);
      }
    }
    #pragma unroll
    for (int cf = 0; cf < 4; ++cf){
      #pragma unroll
      for (int j = 0; j < 4; ++j){
        float sv = sacc[cf][j] * 0.125f;
        if (diag){
          int kj = cf*16 + lo;
          int qr = w*16 + g*4 + j;
          if (kj > qr) sv -= 10000.f;
        }
        sacc[cf][j] = sv;
      }
    }
    float mnew[4], alpha[4], rsum[4];
    #pragma unroll
    for (int j = 0; j < 4; ++j){
      float v = fmaxf(fmaxf(sacc[0][j], sacc[1][j]), fmaxf(sacc[2][j], sacc[3][j]));
      v = fmaxf(v, __shfl_xor(v, 1));
      v = fmaxf(v, __shfl_xor(v, 2));
      v = fmaxf(v, __shfl_xor(v, 4));
      v = fmaxf(v, __shfl_xor(v, 8));
      mnew[j] = fmaxf(m_run[j], v);
      alpha[j] = __expf(m_run[j] - mnew[j]);
      m_run[j] = mnew[j];
      rsum[j] = 0.f;
    }
    #pragma unroll
    for (int cf = 0; cf < 4; ++cf){
      #pragma unroll
      for (int j = 0; j < 4; ++j){
        float pv = __expf(sacc[cf][j] - mnew[j]);
        sacc[cf][j] = pv;
        rsum[j] += pv;
      }
    }
    #pragma unroll
    for (int j = 0; j < 4; ++j){
      float v = rsum[j];
      v += __shfl_xor(v, 1);
      v += __shfl_xor(v, 2);
      v += __shfl_xor(v, 4);
      v += __shfl_xor(v, 8);
      l_run[j] = l_run[j] * alpha[j] + v;
    }
    #pragma unroll
    for (int c = 0; c < 4; ++c)
      #pragma unroll
      for (int j = 0; j < 4; ++j) O[c][j] *= alpha[j];

    #pragma unroll
    for (int cf = 0; cf < 4; ++cf)
      #pragma unroll
      for (int j = 0; j < 4; ++j)
        Plds[w][g*4 + j][cf*16 + lo] = f2bf(sacc[cf][j]);

    #pragma unroll
    for (int ks = 0; ks < 2; ++ks){
      bf16x8 pf = *(const bf16x8*)(&Plds[w][lo][ks*32 + g*8]);
      #pragma unroll
      for (int ocf = 0; ocf < 4; ++ocf){
        int r = ocf*16 + lo;
        int byteoff = r*128 + ((ks*64 + g*16) ^ ((lo & 7) << 4));
        bf16x8 vf = *(const bf16x8*)(&Vl[buf][byteoff >> 1]);
        O[ocf] = __builtin_amdgcn_mfma_f32_16x16x32_bf16(pf, vf, O[ocf], 0, 0, 0);
      }
    }
  };

  stage(0, 0);
  for (int kt = 0; kt <= qt; ++kt){
    __syncthreads();                      // staged loads drained; LDS safe
    if (kt < qt) stage(buf ^ 1, kt + 1);  // async prefetch overlaps compute
    computeTile(kt == qt);
    buf ^= 1;
  }

  float inv[4];
  #pragma unroll
  for (int j = 0; j < 4; ++j) inv[j] = 1.0f / l_run[j];
  #pragma unroll
  for (int ocf = 0; ocf < 4; ++ocf){
    #pragma unroll
    for (int j = 0; j < 4; ++j){
      int d = ocf*16 + lo;
      int qi = qt*64 + w*16 + g*4 + j;
      ctx[((size_t)(b * S_ + qi)) * D_ + h * DH_ + d] = f2bf(O[ocf][j] * inv[j]);
    }
  }
}

// ---------------- launch ----------------
extern "C" void kernel_launch(void* const* d_in, const int* in_sizes, int n_in,
                              void* d_out, int out_size, void* d_ws, size_t ws_size,
                              hipStream_t stream){
  (void)in_sizes; (void)n_in; (void)out_size; (void)ws_size;
  const float* x    = (const float*)d_in[0];
  const float* Wqkv = (const float*)d_in[1];
  const float* bqkv = (const float*)d_in[2];
  const float* Wout = (const float*)d_in[3];
  const float* bout = (const float*)d_in[4];
  float* out = (float*)d_out;

  char* p = (char*)d_ws;
  u16* qkv_bf  = (u16*)p; p += (size_t)4096*3072*2;
  u16* x_bf    = (u16*)p; p += (size_t)4096*1024*2;
  u16* wqkv_bf = (u16*)p; p += (size_t)3072*1024*2;
  u16* wout_bf = (u16*)p; p += (size_t)1024*1024*2;
  u16* q_bf    = (u16*)p; p += (size_t)4096*1024*2;
  u16* k_bf    = (u16*)p; p += (size_t)4096*1024*2;
  u16* vt_bf   = (u16*)p; p += (size_t)4096*1024*2;
  u16* ctx_bf  = (u16*)p; p += (size_t)4096*1024*2;

  cast_bf16<<<4096, 256, 0, stream>>>(x, x_bf, 4096*1024);
  cast_bf16<<<3072, 256, 0, stream>>>(Wqkv, wqkv_bf, 3072*1024);
  cast_bf16<<<1024, 256, 0, stream>>>(Wout, wout_bf, 1024*1024);

  gemm_bt<1><<<dim3(32, 24), 256, 0, stream>>>(x_bf, wqkv_bf, bqkv, qkv_bf, 4096, 3072, 1024);

  rope_split<<<dim3(64, 16), 256, 0, stream>>>(qkv_bf, q_bf, k_bf, vt_bf);

  attn_fwd<<<dim3(64, 16), 256, 0, stream>>>(q_bf, k_bf, vt_bf, ctx_bf);

  gemm_bt<0><<<dim3(32, 8), 256, 0, stream>>>(ctx_bf, wout_bf, bout, out, 4096, 1024, 1024);
}